// Round 12
// baseline (52.892 us; speedup 1.0000x reference)
//
#include <hip/hip_runtime.h>
#include <cstdint>
#include <cstddef>

#define W_ 512
#define H_ 512
#define N_ 8
#define C_ 19
#define HW_ (W_*H_)      // 262144 = 2^18
#define NPIX_ (N_*HW_)   // 2^21

#define TS  32           // output tile side
#define SR  46           // sml region rows (halo 7)
#define SC  48           // sml region cols: [tx0-8, tx0+40)
#define BR  52           // bnd-mask rows per tile: [ty0-10, ty0+42)
#define PP  56           // predT row pitch (54 used)

typedef float   f32x4 __attribute__((ext_vector_type(4)));
typedef float   f32x2 __attribute__((ext_vector_type(2)));
typedef uint8_t u8x2  __attribute__((ext_vector_type(2)));
typedef unsigned long long u64;

// ---------------- K1: channel max/argmax via global_load_lds DMA staging -----
// 512-px chunks; writes sml + pred8 only (predf moved to k_fused).
__global__ __launch_bounds__(256) void k_argmax_sml(
    const float* __restrict__ x, const float* __restrict__ means,
    const float* __restrict__ stdv, float* __restrict__ sml,
    uint8_t* __restrict__ pred8)
{
    __shared__ float xs[C_ * 512];       // 38,912 B
    __shared__ float ms[C_], rs[C_];
    const int tid = threadIdx.x;
    if (tid < C_) {
        ms[tid] = means[tid];
        rs[tid] = __builtin_amdgcn_rcpf(stdv[tid]);
    }

    const int chunk = blockIdx.x;            // 512 px per block, 4096 blocks
    const int n   = chunk >> 9;
    const int p0  = (chunk & 511) << 9;
    const int wv  = tid >> 6, lane = tid & 63;
    const float* xg = x + (size_t)n * C_ * HW_ + p0;

    int cLo = wv * 5;
    int cHi = cLo + 5 > C_ ? C_ : cLo + 5;
    for (int c = cLo; c < cHi; ++c) {
        const float* g = xg + (size_t)c * HW_ + lane * 4;
        #pragma unroll
        for (int t = 0; t < 2; ++t) {
            __builtin_amdgcn_global_load_lds(
                (const __attribute__((address_space(1))) void*)(g + t * 256),
                (__attribute__((address_space(3))) void*)&xs[c * 512 + t * 256],
                16, 0, 0);
        }
    }
    __syncthreads();

    const f32x2* xv = (const f32x2*)xs;
    f32x2 mv = xv[tid];
    int i0 = 0, i1 = 0;
    #pragma unroll
    for (int c = 1; c < C_; ++c) {
        f32x2 v = xv[c * 256 + tid];
        if (v[0] > mv[0]) { mv[0] = v[0]; i0 = c; }
        if (v[1] > mv[1]) { mv[1] = v[1]; i1 = c; }
    }
    const int pix = chunk * 512 + tid * 2;
    f32x2 s; u8x2 pc;
    s[0] = (mv[0] - ms[i0]) * rs[i0];  pc[0] = (uint8_t)i0;
    s[1] = (mv[1] - ms[i1]) * rs[i1];  pc[1] = (uint8_t)i1;
    *(f32x2*)(sml + pix) = s;
    *(u8x2*)(pred8 + pix) = pc;
}

// ---------------- K2: fused bnd + masks + hot/cold smooth + conv + predf -----
__global__ __launch_bounds__(256) void k_fused(
    const float* __restrict__ sml_g, const uint8_t* __restrict__ pred8,
    const float* __restrict__ gk, float* __restrict__ out,
    float* __restrict__ predf)
{
    __shared__ uint8_t predT[54*PP];        // (gy,gx) = (ty0+i-11, tx0+j-11)
    __shared__ float smlA[SR*SC];
    __shared__ float smlB[SR*SC];           // staging; aliased as htmp
    __shared__ u64 M0[BR], E1[BR], E2[BR], E3[BR], VM[BR];
    __shared__ u64 NBM[4][BR];
    __shared__ float g7[7];
    __shared__ int tACT;

    const int tid = threadIdx.x;
    const int wv = tid >> 6, lane = tid & 63;
    const int bx = blockIdx.x, by = blockIdx.y, n = blockIdx.z;
    const int tx0 = bx * TS, ty0 = by * TS;
    const float*   sg = sml_g + (size_t)n * HW_;
    const uint8_t* pg = pred8 + (size_t)n * HW_;

    if (tid == 0) tACT = 0;
    if (tid < 7) g7[tid] = gk[21 + tid] / sqrtf(gk[24]);   // kk = outer(g,g)

    // ---- load pred 54x54 halo, clamp-to-edge (exact for 3x3 minmax: a
    // clamped tap duplicates an in-window in-bounds tap) ----
    for (int s = tid; s < 54*54; s += 256) {
        int i = s / 54, j = s - i * 54;
        int gy = ty0 + i - 11; gy = gy < 0 ? 0 : (gy > H_-1 ? H_-1 : gy);
        int gx = tx0 + j - 11; gx = gx < 0 ? 0 : (gx > W_-1 ? W_-1 : gx);
        predT[i*PP + j] = pg[gy*W_ + gx];
    }
    // ---- validity masks: VM[i] bit b valid iff (ty0+i-10, tx0+b-10) in-image
    if (tid < BR) {
        int gy  = ty0 + tid - 10;
        int bx0 = tx0 - 10;
        u64 vm = 0;
        if (gy >= 0 && gy < H_) {
            int lo = bx0 < 0 ? -bx0 : 0;
            int hi = (512 - bx0) < BR ? (512 - bx0) : BR;
            if (hi > lo) vm = ((1ULL << (hi - lo)) - 1ULL) << lo;
        }
        VM[tid] = vm;
    }
    __syncthreads();

    // ---- boundary bits via ballot: wave wv does rows wv, wv+4, ... ----
    for (int i = wv; i < BR; i += 4) {
        bool b = false;
        if (lane < BR) {
            const uint8_t* p = &predT[(i+1)*PP + (lane+1)];
            int c  = p[0];
            int up = p[-PP], dn = p[PP], lf = p[-1], rt = p[1];
            int mx = max(max(c, up), max(dn, max(lf, rt)));     // cross dilate
            int mn = min(min(c, up), min(dn, min(lf, rt)));     // full 3x3 erode
            mn = min(mn, min(min((int)p[-PP-1], (int)p[-PP+1]),
                             min((int)p[ PP-1], (int)p[ PP+1])));
            b = (mx != mn);
        }
        u64 m = __ballot(b);
        if (lane == 0) M0[i] = m & VM[i];
    }
    __syncthreads();

    // ---- predf output for this tile (from predT core) ----
    {
        int oy = tid >> 3, ox4 = tid & 7;       // 32 rows x 8 float4
        f32x4 pf;
        #pragma unroll
        for (int k = 0; k < 4; ++k)
            pf[k] = (float)predT[(oy + 11)*PP + (ox4*4 + k + 11)];
        *(f32x4*)(predf + (size_t)n*HW_ + (size_t)(ty0 + oy)*W_ + tx0 + ox4*4) = pf;
    }

    // ---- active detection from NB0 = ~M0 & VM ----
    u64 actRow = 0;
    if (tid < SR) {
        int bi = tid + 3;
        u64 nbU = ~M0[bi-1] & VM[bi-1];
        u64 nbC = ~M0[bi  ] & VM[bi  ];
        u64 nbD = ~M0[bi+1] & VM[bi+1];
        u64 U = nbU | nbC | nbD;
        u64 A = (U >> 1) | (U >> 2) | (U >> 3);
        int lo = tx0 == 0 ? 8 : 0;
        int hi = tx0 == (W_-TS) ? 40 : SC;
        u64 CV = (hi - lo >= 64) ? ~0ULL : (((1ULL << (hi - lo)) - 1ULL) << lo);
        actRow = A & CV;
        int gy = ty0 + tid - 7;
        if ((unsigned)gy >= (unsigned)H_) actRow = 0;
        if (actRow) tACT = 1;                              // benign race
    }
    __syncthreads();

    if (!tACT) {
        // ======== HOT PATH: conv only; load rows [4,42) x cols [4,44) ========
        for (int s = tid; s < 38 * 10; s += 256) {
            int q  = s / 10;
            int ly = 4 + q, lx4 = s - q * 10;
            int gy = ty0 + ly - 7;
            int gx = tx0 - 4 + lx4 * 4;
            f32x4 v = {0.f, 0.f, 0.f, 0.f};
            if ((unsigned)gy < (unsigned)H_ && (unsigned)gx < (unsigned)W_)
                v = *(const f32x4*)(sg + (size_t)gy * W_ + gx);
            *(f32x4*)&smlA[ly * SC + 4 + lx4 * 4] = v;
        }
        __syncthreads();
        float* htmp = smlB;
        for (int s = tid; s < 38 * 32; s += 256) {
            int hy = s >> 5, hx = s & 31;
            const float* p = &smlA[(hy + 4)*SC + (hx + 5)];
            htmp[hy*33 + hx] = g7[0]*p[0] + g7[1]*p[1] + g7[2]*p[2] + g7[3]*p[3]
                             + g7[4]*p[4] + g7[5]*p[5] + g7[6]*p[6];
        }
        __syncthreads();
        for (int s = tid; s < TS*TS; s += 256) {
            int oy = s >> 5, ox = s & 31;
            const float* p = &htmp[oy*33 + ox];
            float a = g7[0]*p[0]   + g7[1]*p[33]  + g7[2]*p[66]  + g7[3]*p[99]
                    + g7[4]*p[132] + g7[5]*p[165] + g7[6]*p[198];
            out[(size_t)n*HW_ + (size_t)(ty0 + oy)*W_ + (tx0 + ox)] = a;
        }
        return;
    }

    // ======== COLD PATH ========
    if (bx > 0 && bx < (W_/TS - 1)) {
        for (int s = tid; s < SR * (SC/4); s += 256) {
            int ly = s / (SC/4), j = s - ly * (SC/4);
            int gy = ty0 + ly - 7;
            f32x4 v = {0.f, 0.f, 0.f, 0.f};
            if ((unsigned)gy < (unsigned)H_)
                v = *(const f32x4*)(sg + (size_t)gy * W_ + (tx0 - 8) + j * 4);
            *(f32x4*)&smlA[ly * SC + j * 4] = v;
        }
    } else {
        for (int s = tid; s < SR * SC; s += 256) {
            int ly = s / SC, lx = s - ly * SC;
            int gy = ty0 + ly - 7, gx = tx0 + lx - 8;
            float v = 0.f;
            if ((unsigned)gy < (unsigned)H_ && (unsigned)gx < (unsigned)W_)
                v = sg[(size_t)gy * W_ + gx];
            smlA[ly * SC + lx] = v;
        }
    }
    __syncthreads();

    if (tid < BR) {
        u64 a = M0[tid], u = tid > 0 ? M0[tid-1] : 0, d = tid < BR-1 ? M0[tid+1] : 0;
        E1[tid] = a | (a << 1) | (a >> 1) | u | d;
    }
    __syncthreads();
    if (tid < BR) {
        u64 a = E1[tid], u = tid > 0 ? E1[tid-1] : 0, d = tid < BR-1 ? E1[tid+1] : 0;
        E2[tid] = a | (a << 1) | (a >> 1) | u | d;
    }
    __syncthreads();
    if (tid < BR) {
        u64 a = E2[tid], u = tid > 0 ? E2[tid-1] : 0, d = tid < BR-1 ? E2[tid+1] : 0;
        E3[tid] = a | (a << 1) | (a >> 1) | u | d;
    }
    __syncthreads();
    {
        int r = tid >> 6, i = tid & 63;
        if (i < BR) {
            u64 e = (r == 0) ? M0[i] : (r == 1) ? E1[i] : (r == 2) ? E2[i] : E3[i];
            NBM[r][i] = ~e & VM[i];
        }
    }
    __syncthreads();

    #pragma unroll
    for (int k = 0; k < 4; ++k) {
        const int r = 3 - k;
        const u64 colmask = ((1ULL << (44 - 2*k)) - 1ULL) << (2 + k);
        u64 mwork = 0;
        if (tid >= 1 + k && tid < 45 - k && tid < SR)
            mwork = actRow & colmask;
        u64 mm = mwork;
        while (mm) {
            int lx = __ffsll(mm) - 1; mm &= mm - 1;
            int bi = tid + 3, sh = lx + 1;
            u64 fu = (NBM[r][bi-1] >> sh) & 7ULL;
            u64 fc = (NBM[r][bi  ] >> sh) & 7ULL;
            u64 fd = (NBM[r][bi+1] >> sh) & 7ULL;
            float c = smlA[tid*SC + lx];
            float o;
            if (((fc >> 1) & 1ULL) || !(fu | fc | fd)) {
                o = c;
            } else {
                int cnt = __popcll(fu) + __popcll(fc) + __popcll(fd);
                float sum = 0.f;
                const float* r0 = &smlA[(tid-1)*SC + lx];
                const float* r1 = &smlA[(tid  )*SC + lx];
                const float* r2 = &smlA[(tid+1)*SC + lx];
                if (fu & 1) sum += r0[-1];
                if (fu & 2) sum += r0[0];
                if (fu & 4) sum += r0[1];
                if (fc & 1) sum += r1[-1];
                if (fc & 4) sum += r1[1];
                if (fd & 1) sum += r2[-1];
                if (fd & 2) sum += r2[0];
                if (fd & 4) sum += r2[1];
                o = sum / (float)cnt;
            }
            smlB[tid*SC + lx] = o;
        }
        __syncthreads();
        mm = mwork;
        while (mm) {
            int lx = __ffsll(mm) - 1; mm &= mm - 1;
            smlA[tid*SC + lx] = smlB[tid*SC + lx];
        }
        __syncthreads();
    }

    float* htmp = smlB;
    for (int s = tid; s < 38 * 32; s += 256) {
        int hy = s >> 5, hx = s & 31;
        const float* p = &smlA[(hy + 4)*SC + (hx + 5)];
        htmp[hy*33 + hx] = g7[0]*p[0] + g7[1]*p[1] + g7[2]*p[2] + g7[3]*p[3]
                         + g7[4]*p[4] + g7[5]*p[5] + g7[6]*p[6];
    }
    __syncthreads();
    for (int s = tid; s < TS*TS; s += 256) {
        int oy = s >> 5, ox = s & 31;
        const float* p = &htmp[oy*33 + ox];
        float a = g7[0]*p[0]   + g7[1]*p[33]  + g7[2]*p[66]  + g7[3]*p[99]
                + g7[4]*p[132] + g7[5]*p[165] + g7[6]*p[198];
        out[(size_t)n*HW_ + (size_t)(ty0 + oy)*W_ + (tx0 + ox)] = a;
    }
}

extern "C" void kernel_launch(void* const* d_in, const int* in_sizes, int n_in,
                              void* d_out, int out_size, void* d_ws, size_t ws_size,
                              hipStream_t stream)
{
    const float* x     = (const float*)d_in[0];
    const float* means = (const float*)d_in[1];
    const float* stdv  = (const float*)d_in[2];
    const float* gk    = (const float*)d_in[3];
    float* out_sml  = (float*)d_out;
    float* out_pred = (float*)d_out + NPIX_;

    char* ws = (char*)d_ws;
    float*   sml   = (float*)(ws);                 // 8,388,608 B
    uint8_t* pred8 = (uint8_t*)(ws + 8388608);     // 2,097,152 B

    k_argmax_sml<<<NPIX_/512, 256, 0, stream>>>(x, means, stdv, sml, pred8);
    dim3 fgrd(W_/TS, H_/TS, N_);
    k_fused<<<fgrd, 256, 0, stream>>>(sml, pred8, gk, out_sml, out_pred);
}

// Round 13
// 52.164 us; speedup vs baseline: 1.0139x; 1.0139x over previous
//
#include <hip/hip_runtime.h>
#include <cstdint>
#include <cstddef>

#define W_ 512
#define H_ 512
#define N_ 8
#define C_ 19
#define HW_ (W_*H_)      // 262144 = 2^18
#define NPIX_ (N_*HW_)   // 2^21

#define TS  32           // output tile side
#define SR  46           // sml region rows (halo 7)
#define SC  48           // sml region cols: [tx0-8, tx0+40)
#define BR  52           // bnd-mask rows per tile: [ty0-10, ty0+42)

typedef float   f32x4 __attribute__((ext_vector_type(4)));
typedef float   f32x2 __attribute__((ext_vector_type(2)));
typedef uint8_t u8x2  __attribute__((ext_vector_type(2)));
typedef unsigned long long u64;

// ---------------- K1: persistent dbuf DMA argmax -----------------------------
// R13: 512 persistent blocks (2/CU, 76 KB LDS = 2 x 19x512 f32 buffers), each
// runs 8 chunks. Pipeline: issue DMA(i+1) -> vmcnt(nIssue) [counted, never 0
// mid-loop] -> raw s_barrier -> compute(i) -> barrier. Next chunk's HBM reads
// stay in flight under compute (T3/T4 pattern).
__global__ __launch_bounds__(256) void k_argmax_sml(
    const float* __restrict__ x, const float* __restrict__ means,
    const float* __restrict__ stdv, float* __restrict__ sml,
    uint8_t* __restrict__ pred8, float* __restrict__ predf)
{
    __shared__ float xs0[C_ * 512];      // 38,912 B
    __shared__ float xs1[C_ * 512];      // 38,912 B
    __shared__ float ms[C_], rs[C_];
    const int tid = threadIdx.x;
    if (tid < C_) {
        ms[tid] = means[tid];
        rs[tid] = __builtin_amdgcn_rcpf(stdv[tid]);
    }
    const int wv = tid >> 6, lane = tid & 63;
    const int cLo = wv * 5;
    const int cHi = cLo + 5 > C_ ? C_ : cLo + 5;    // wave3: 4 channels
    const int bid = blockIdx.x;

    auto issue = [&](int chunk, float* buf) {
        const int n  = chunk >> 9;
        const int p0 = (chunk & 511) << 9;
        const float* xg = x + (size_t)n * C_ * HW_ + p0;
        for (int c = cLo; c < cHi; ++c) {
            const float* g = xg + (size_t)c * HW_ + lane * 4;
            __builtin_amdgcn_global_load_lds(
                (const __attribute__((address_space(1))) void*)g,
                (__attribute__((address_space(3))) void*)&buf[c * 512], 16, 0, 0);
            __builtin_amdgcn_global_load_lds(
                (const __attribute__((address_space(1))) void*)(g + 256),
                (__attribute__((address_space(3))) void*)&buf[c * 512 + 256], 16, 0, 0);
        }
    };

    issue(bid, xs0);                                 // prologue: chunk 0 in flight
    #pragma unroll
    for (int it = 0; it < 8; ++it) {
        float* cur = (it & 1) ? xs1 : xs0;
        float* nxt = (it & 1) ? xs0 : xs1;
        if (it < 7) issue(bid + (it + 1) * 512, nxt);
        __builtin_amdgcn_sched_barrier(0);
        if (it < 7) {
            if (wv < 3) asm volatile("s_waitcnt vmcnt(10)" ::: "memory");
            else        asm volatile("s_waitcnt vmcnt(8)"  ::: "memory");
        } else {
            asm volatile("s_waitcnt vmcnt(0)" ::: "memory");
        }
        __builtin_amdgcn_s_barrier();                // all waves' chunk-it data in LDS
        __builtin_amdgcn_sched_barrier(0);

        const int chunk = bid + it * 512;
        const f32x2* xv = (const f32x2*)cur;
        f32x2 mv = xv[tid];
        int i0 = 0, i1 = 0;
        #pragma unroll
        for (int c = 1; c < C_; ++c) {
            f32x2 v = xv[c * 256 + tid];
            if (v[0] > mv[0]) { mv[0] = v[0]; i0 = c; }
            if (v[1] > mv[1]) { mv[1] = v[1]; i1 = c; }
        }
        const int pix = chunk * 512 + tid * 2;
        f32x2 s, pf; u8x2 pc;
        s[0] = (mv[0] - ms[i0]) * rs[i0];  pf[0] = (float)i0;  pc[0] = (uint8_t)i0;
        s[1] = (mv[1] - ms[i1]) * rs[i1];  pf[1] = (float)i1;  pc[1] = (uint8_t)i1;
        *(f32x2*)(sml + pix) = s;
        *(u8x2*)(pred8 + pix) = pc;
        __builtin_nontemporal_store(pf, (f32x2*)(predf + pix));
        __builtin_amdgcn_s_barrier();                // cur free for overwrite at it+1
    }
}

// ---------------- K2: boundary bits -> packed row masks (8 u64 per row) ------
__global__ __launch_bounds__(256) void k_bnd(
    const uint8_t* __restrict__ pred8, u64* __restrict__ bndM)
{
    int gid  = blockIdx.x * 256 + threadIdx.x;
    int lane = gid & 63;
    int wave = gid >> 6;
    int w = wave & 7;
    int y = (wave >> 3) & 511;
    int n = wave >> 12;
    int xx = w * 64 + lane;
    const uint8_t* pc = pred8 + (size_t)n * HW_ + y * W_ + xx;
    int c = pc[0];
    bool u = y > 0, d = y < H_-1, l = xx > 0, r = xx < W_-1;
    int up = u ? pc[-W_] : c;
    int dn = d ? pc[ W_] : c;
    int lf = l ? pc[-1]  : c;
    int rt = r ? pc[ 1]  : c;
    int mx = max(max(c, up), max(dn, max(lf, rt)));       // cross dilate
    int mn = min(min(c, up), min(dn, min(lf, rt)));       // full 3x3 erode
    int c00 = (u && l) ? pc[-W_-1] : c;
    int c01 = (u && r) ? pc[-W_+1] : c;
    int c10 = (d && l) ? pc[ W_-1] : c;
    int c11 = (d && r) ? pc[ W_+1] : c;
    mn = min(mn, min(min(c00, c01), min(c10, c11)));
    u64 m = __ballot(mx != mn);
    if (lane == 0) bndM[((size_t)n * 512 + y) * 8 + w] = m;
}

// ---------------- K3: fused masks + hot/cold paths + separable conv ----------
__global__ __launch_bounds__(256) void k_fused(
    const float* __restrict__ sml_g, const u64* __restrict__ bndM,
    const float* __restrict__ gk, float* __restrict__ out)
{
    __shared__ float smlA[SR*SC];
    __shared__ float smlB[SR*SC];           // staging; aliased as htmp
    __shared__ u64 M0[BR], E1[BR], E2[BR], E3[BR], VM[BR];
    __shared__ u64 NBM[4][BR];
    __shared__ float g7[7];
    __shared__ int tACT;

    const int tid = threadIdx.x;
    const int bx = blockIdx.x, by = blockIdx.y, n = blockIdx.z;
    const int tx0 = bx * TS, ty0 = by * TS;
    const float* sg = sml_g + (size_t)n * HW_;

    if (tid == 0) tACT = 0;
    if (tid < 7) g7[tid] = gk[21 + tid] / sqrtf(gk[24]);   // kk = outer(g,g)

    // ---- load 52 bnd row-masks (window [tx0-10, tx0+42)) + validity masks ----
    if (tid < BR) {
        int gy = ty0 + tid - 10;
        int bx0 = tx0 - 10;
        u64 m = 0, vm = 0;
        if (gy >= 0 && gy < H_) {
            const u64* row = bndM + ((size_t)n * 512 + gy) * 8;
            int sft = bx0 & 63;
            int wi  = bx0 >> 6;                           // arithmetic: -10 -> -1
            u64 w0 = (wi >= 0) ? row[wi] : 0ULL;
            u64 w1 = (wi + 1 <= 7) ? row[wi + 1] : 0ULL;
            m = sft ? ((w0 >> sft) | (w1 << (64 - sft))) : w0;
            int lo = bx0 < 0 ? -bx0 : 0;
            int hi = (512 - bx0) < BR ? (512 - bx0) : BR;
            if (hi > lo) vm = ((1ULL << (hi - lo)) - 1ULL) << lo;
        }
        M0[tid] = m;
        VM[tid] = vm;
    }
    __syncthreads();

    // ---- active detection from NB0 = ~M0 & VM (no dilations needed) ----
    u64 actRow = 0;
    if (tid < SR) {
        int bi = tid + 3;
        u64 nbU = ~M0[bi-1] & VM[bi-1];
        u64 nbC = ~M0[bi  ] & VM[bi  ];
        u64 nbD = ~M0[bi+1] & VM[bi+1];
        u64 U = nbU | nbC | nbD;
        u64 A = (U >> 1) | (U >> 2) | (U >> 3);
        int lo = tx0 == 0 ? 8 : 0;
        int hi = tx0 == (W_-TS) ? 40 : SC;
        u64 CV = (hi - lo >= 64) ? ~0ULL : (((1ULL << (hi - lo)) - 1ULL) << lo);
        actRow = A & CV;
        int gy = ty0 + tid - 7;
        if ((unsigned)gy >= (unsigned)H_) actRow = 0;
        if (actRow) tACT = 1;                              // benign race
    }
    __syncthreads();

    if (!tACT) {
        // ======== HOT PATH: conv only; load rows [4,42) x cols [4,44) ========
        for (int s = tid; s < 38 * 10; s += 256) {
            int q  = s / 10;
            int ly = 4 + q, lx4 = s - q * 10;
            int gy = ty0 + ly - 7;
            int gx = tx0 - 4 + lx4 * 4;
            f32x4 v = {0.f, 0.f, 0.f, 0.f};
            if ((unsigned)gy < (unsigned)H_ && (unsigned)gx < (unsigned)W_)
                v = *(const f32x4*)(sg + (size_t)gy * W_ + gx);
            *(f32x4*)&smlA[ly * SC + 4 + lx4 * 4] = v;
        }
        __syncthreads();
        float* htmp = smlB;
        for (int s = tid; s < 38 * 32; s += 256) {
            int hy = s >> 5, hx = s & 31;
            const float* p = &smlA[(hy + 4)*SC + (hx + 5)];
            htmp[hy*33 + hx] = g7[0]*p[0] + g7[1]*p[1] + g7[2]*p[2] + g7[3]*p[3]
                             + g7[4]*p[4] + g7[5]*p[5] + g7[6]*p[6];
        }
        __syncthreads();
        for (int s = tid; s < TS*TS; s += 256) {
            int oy = s >> 5, ox = s & 31;
            const float* p = &htmp[oy*33 + ox];
            float a = g7[0]*p[0]   + g7[1]*p[33]  + g7[2]*p[66]  + g7[3]*p[99]
                    + g7[4]*p[132] + g7[5]*p[165] + g7[6]*p[198];
            out[(size_t)n*HW_ + (size_t)(ty0 + oy)*W_ + (tx0 + ox)] = a;
        }
        return;
    }

    // ======== COLD PATH ========
    if (bx > 0 && bx < (W_/TS - 1)) {
        for (int s = tid; s < SR * (SC/4); s += 256) {
            int ly = s / (SC/4), j = s - ly * (SC/4);
            int gy = ty0 + ly - 7;
            f32x4 v = {0.f, 0.f, 0.f, 0.f};
            if ((unsigned)gy < (unsigned)H_)
                v = *(const f32x4*)(sg + (size_t)gy * W_ + (tx0 - 8) + j * 4);
            *(f32x4*)&smlA[ly * SC + j * 4] = v;
        }
    } else {
        for (int s = tid; s < SR * SC; s += 256) {
            int ly = s / SC, lx = s - ly * SC;
            int gy = ty0 + ly - 7, gx = tx0 + lx - 8;
            float v = 0.f;
            if ((unsigned)gy < (unsigned)H_ && (unsigned)gx < (unsigned)W_)
                v = sg[(size_t)gy * W_ + gx];
            smlA[ly * SC + lx] = v;
        }
    }
    __syncthreads();

    if (tid < BR) {
        u64 a = M0[tid], u = tid > 0 ? M0[tid-1] : 0, d = tid < BR-1 ? M0[tid+1] : 0;
        E1[tid] = a | (a << 1) | (a >> 1) | u | d;
    }
    __syncthreads();
    if (tid < BR) {
        u64 a = E1[tid], u = tid > 0 ? E1[tid-1] : 0, d = tid < BR-1 ? E1[tid+1] : 0;
        E2[tid] = a | (a << 1) | (a >> 1) | u | d;
    }
    __syncthreads();
    if (tid < BR) {
        u64 a = E2[tid], u = tid > 0 ? E2[tid-1] : 0, d = tid < BR-1 ? E2[tid+1] : 0;
        E3[tid] = a | (a << 1) | (a >> 1) | u | d;
    }
    __syncthreads();
    {
        int r = tid >> 6, i = tid & 63;
        if (i < BR) {
            u64 e = (r == 0) ? M0[i] : (r == 1) ? E1[i] : (r == 2) ? E2[i] : E3[i];
            NBM[r][i] = ~e & VM[i];
        }
    }
    __syncthreads();

    #pragma unroll
    for (int k = 0; k < 4; ++k) {
        const int r = 3 - k;
        const u64 colmask = ((1ULL << (44 - 2*k)) - 1ULL) << (2 + k);
        u64 mwork = 0;
        if (tid >= 1 + k && tid < 45 - k && tid < SR)
            mwork = actRow & colmask;
        u64 mm = mwork;
        while (mm) {
            int lx = __ffsll(mm) - 1; mm &= mm - 1;
            int bi = tid + 3, sh = lx + 1;
            u64 fu = (NBM[r][bi-1] >> sh) & 7ULL;
            u64 fc = (NBM[r][bi  ] >> sh) & 7ULL;
            u64 fd = (NBM[r][bi+1] >> sh) & 7ULL;
            float c = smlA[tid*SC + lx];
            float o;
            if (((fc >> 1) & 1ULL) || !(fu | fc | fd)) {
                o = c;
            } else {
                int cnt = __popcll(fu) + __popcll(fc) + __popcll(fd);
                float sum = 0.f;
                const float* r0 = &smlA[(tid-1)*SC + lx];
                const float* r1 = &smlA[(tid  )*SC + lx];
                const float* r2 = &smlA[(tid+1)*SC + lx];
                if (fu & 1) sum += r0[-1];
                if (fu & 2) sum += r0[0];
                if (fu & 4) sum += r0[1];
                if (fc & 1) sum += r1[-1];
                if (fc & 4) sum += r1[1];
                if (fd & 1) sum += r2[-1];
                if (fd & 2) sum += r2[0];
                if (fd & 4) sum += r2[1];
                o = sum / (float)cnt;
            }
            smlB[tid*SC + lx] = o;
        }
        __syncthreads();
        mm = mwork;
        while (mm) {
            int lx = __ffsll(mm) - 1; mm &= mm - 1;
            smlA[tid*SC + lx] = smlB[tid*SC + lx];
        }
        __syncthreads();
    }

    float* htmp = smlB;
    for (int s = tid; s < 38 * 32; s += 256) {
        int hy = s >> 5, hx = s & 31;
        const float* p = &smlA[(hy + 4)*SC + (hx + 5)];
        htmp[hy*33 + hx] = g7[0]*p[0] + g7[1]*p[1] + g7[2]*p[2] + g7[3]*p[3]
                         + g7[4]*p[4] + g7[5]*p[5] + g7[6]*p[6];
    }
    __syncthreads();
    for (int s = tid; s < TS*TS; s += 256) {
        int oy = s >> 5, ox = s & 31;
        const float* p = &htmp[oy*33 + ox];
        float a = g7[0]*p[0]   + g7[1]*p[33]  + g7[2]*p[66]  + g7[3]*p[99]
                + g7[4]*p[132] + g7[5]*p[165] + g7[6]*p[198];
        out[(size_t)n*HW_ + (size_t)(ty0 + oy)*W_ + (tx0 + ox)] = a;
    }
}

extern "C" void kernel_launch(void* const* d_in, const int* in_sizes, int n_in,
                              void* d_out, int out_size, void* d_ws, size_t ws_size,
                              hipStream_t stream)
{
    const float* x     = (const float*)d_in[0];
    const float* means = (const float*)d_in[1];
    const float* stdv  = (const float*)d_in[2];
    const float* gk    = (const float*)d_in[3];
    float* out_sml  = (float*)d_out;
    float* out_pred = (float*)d_out + NPIX_;

    char* ws = (char*)d_ws;
    float*   sml   = (float*)(ws);                 // 8,388,608 B
    uint8_t* pred8 = (uint8_t*)(ws + 8388608);     // 2,097,152 B
    u64*     bndM  = (u64*)(ws + 10485760);        //   262,144 B

    k_argmax_sml<<<512, 256, 0, stream>>>(x, means, stdv, sml, pred8, out_pred);
    k_bnd<<<NPIX_/256, 256, 0, stream>>>(pred8, bndM);
    dim3 fgrd(W_/TS, H_/TS, N_);
    k_fused<<<fgrd, 256, 0, stream>>>(sml, bndM, gk, out_sml);
}

// Round 14
// 50.705 us; speedup vs baseline: 1.0431x; 1.0288x over previous
//
#include <hip/hip_runtime.h>
#include <cstdint>
#include <cstddef>

#define W_ 512
#define H_ 512
#define N_ 8
#define C_ 19
#define HW_ (W_*H_)      // 262144 = 2^18
#define NPIX_ (N_*HW_)   // 2^21

#define TS  32           // output tile side
#define SR  46           // sml region rows (halo 7)
#define SC  48           // sml region cols: [tx0-8, tx0+40)
#define BR  52           // bnd-mask rows per tile: [ty0-10, ty0+42)

typedef float   f32x4 __attribute__((ext_vector_type(4)));
typedef float   f32x2 __attribute__((ext_vector_type(2)));
typedef uint8_t u8x2  __attribute__((ext_vector_type(2)));
typedef unsigned long long u64;

// ---------------- K1: channel max/argmax via global_load_lds DMA staging -----
// R14: R11 structure (4096 blocks, 512-px chunks); predf write moved to k_bnd
// (K1 is BW-saturated at ~4.8 TB/s; k_bnd is latency-bound and absorbs the
// 8.4 MB write for free).
__global__ __launch_bounds__(256) void k_argmax_sml(
    const float* __restrict__ x, const float* __restrict__ means,
    const float* __restrict__ stdv, float* __restrict__ sml,
    uint8_t* __restrict__ pred8)
{
    __shared__ float xs[C_ * 512];       // 38,912 B
    __shared__ float ms[C_], rs[C_];
    const int tid = threadIdx.x;
    if (tid < C_) {
        ms[tid] = means[tid];
        rs[tid] = __builtin_amdgcn_rcpf(stdv[tid]);
    }

    const int chunk = blockIdx.x;            // 512 px per block, 4096 blocks
    const int n   = chunk >> 9;
    const int p0  = (chunk & 511) << 9;
    const int wv  = tid >> 6, lane = tid & 63;
    const float* xg = x + (size_t)n * C_ * HW_ + p0;

    int cLo = wv * 5;
    int cHi = cLo + 5 > C_ ? C_ : cLo + 5;   // wave3: 4 channels
    for (int c = cLo; c < cHi; ++c) {
        const float* g = xg + (size_t)c * HW_ + lane * 4;
        #pragma unroll
        for (int t = 0; t < 2; ++t) {
            __builtin_amdgcn_global_load_lds(
                (const __attribute__((address_space(1))) void*)(g + t * 256),
                (__attribute__((address_space(3))) void*)&xs[c * 512 + t * 256],
                16, 0, 0);
        }
    }
    __syncthreads();

    const f32x2* xv = (const f32x2*)xs;
    f32x2 mv = xv[tid];
    int i0 = 0, i1 = 0;
    #pragma unroll
    for (int c = 1; c < C_; ++c) {
        f32x2 v = xv[c * 256 + tid];
        if (v[0] > mv[0]) { mv[0] = v[0]; i0 = c; }
        if (v[1] > mv[1]) { mv[1] = v[1]; i1 = c; }
    }
    const int pix = chunk * 512 + tid * 2;
    f32x2 s; u8x2 pc;
    s[0] = (mv[0] - ms[i0]) * rs[i0];  pc[0] = (uint8_t)i0;
    s[1] = (mv[1] - ms[i1]) * rs[i1];  pc[1] = (uint8_t)i1;
    *(f32x2*)(sml + pix) = s;
    *(u8x2*)(pred8 + pix) = pc;
}

// ---------------- K2: boundary bits -> row masks; also writes predf ----------
__global__ __launch_bounds__(256) void k_bnd(
    const uint8_t* __restrict__ pred8, u64* __restrict__ bndM,
    float* __restrict__ predf)
{
    int gid  = blockIdx.x * 256 + threadIdx.x;
    int lane = gid & 63;
    int wave = gid >> 6;
    int w = wave & 7;
    int y = (wave >> 3) & 511;
    int n = wave >> 12;
    int xx = w * 64 + lane;
    const size_t pix = (size_t)n * HW_ + y * W_ + xx;
    const uint8_t* pc = pred8 + pix;
    int c = pc[0];
    bool u = y > 0, d = y < H_-1, l = xx > 0, r = xx < W_-1;
    int up = u ? pc[-W_] : c;
    int dn = d ? pc[ W_] : c;
    int lf = l ? pc[-1]  : c;
    int rt = r ? pc[ 1]  : c;
    int mx = max(max(c, up), max(dn, max(lf, rt)));       // cross dilate
    int mn = min(min(c, up), min(dn, min(lf, rt)));       // full 3x3 erode
    int c00 = (u && l) ? pc[-W_-1] : c;
    int c01 = (u && r) ? pc[-W_+1] : c;
    int c10 = (d && l) ? pc[ W_-1] : c;
    int c11 = (d && r) ? pc[ W_+1] : c;
    mn = min(mn, min(min(c00, c01), min(c10, c11)));
    __builtin_nontemporal_store((float)c, predf + pix);   // coalesced 256B/wave
    u64 m = __ballot(mx != mn);
    if (lane == 0) bndM[((size_t)n * 512 + y) * 8 + w] = m;
}

// ---------------- K3: fused masks + hot/cold paths + separable conv ----------
__global__ __launch_bounds__(256) void k_fused(
    const float* __restrict__ sml_g, const u64* __restrict__ bndM,
    const float* __restrict__ gk, float* __restrict__ out)
{
    __shared__ float smlA[SR*SC];
    __shared__ float smlB[SR*SC];           // staging; aliased as htmp
    __shared__ u64 M0[BR], E1[BR], E2[BR], E3[BR], VM[BR];
    __shared__ u64 NBM[4][BR];
    __shared__ float g7[7];
    __shared__ int tACT;

    const int tid = threadIdx.x;
    const int bx = blockIdx.x, by = blockIdx.y, n = blockIdx.z;
    const int tx0 = bx * TS, ty0 = by * TS;
    const float* sg = sml_g + (size_t)n * HW_;

    if (tid == 0) tACT = 0;
    if (tid < 7) g7[tid] = gk[21 + tid] / sqrtf(gk[24]);   // kk = outer(g,g)

    // ---- load 52 bnd row-masks (window [tx0-10, tx0+42)) + validity masks ----
    if (tid < BR) {
        int gy = ty0 + tid - 10;
        int bx0 = tx0 - 10;
        u64 m = 0, vm = 0;
        if (gy >= 0 && gy < H_) {
            const u64* row = bndM + ((size_t)n * 512 + gy) * 8;
            int sft = bx0 & 63;
            int wi  = bx0 >> 6;                           // arithmetic: -10 -> -1
            u64 w0 = (wi >= 0) ? row[wi] : 0ULL;
            u64 w1 = (wi + 1 <= 7) ? row[wi + 1] : 0ULL;
            m = sft ? ((w0 >> sft) | (w1 << (64 - sft))) : w0;
            int lo = bx0 < 0 ? -bx0 : 0;
            int hi = (512 - bx0) < BR ? (512 - bx0) : BR;
            if (hi > lo) vm = ((1ULL << (hi - lo)) - 1ULL) << lo;
        }
        M0[tid] = m;
        VM[tid] = vm;
    }
    __syncthreads();

    // ---- active detection from NB0 = ~M0 & VM ----
    u64 actRow = 0;
    if (tid < SR) {
        int bi = tid + 3;
        u64 nbU = ~M0[bi-1] & VM[bi-1];
        u64 nbC = ~M0[bi  ] & VM[bi  ];
        u64 nbD = ~M0[bi+1] & VM[bi+1];
        u64 U = nbU | nbC | nbD;
        u64 A = (U >> 1) | (U >> 2) | (U >> 3);
        int lo = tx0 == 0 ? 8 : 0;
        int hi = tx0 == (W_-TS) ? 40 : SC;
        u64 CV = (hi - lo >= 64) ? ~0ULL : (((1ULL << (hi - lo)) - 1ULL) << lo);
        actRow = A & CV;
        int gy = ty0 + tid - 7;
        if ((unsigned)gy >= (unsigned)H_) actRow = 0;
        if (actRow) tACT = 1;                              // benign race
    }
    __syncthreads();

    if (!tACT) {
        // ======== HOT PATH: conv only; load rows [4,42) x cols [4,44) ========
        for (int s = tid; s < 38 * 10; s += 256) {
            int q  = s / 10;
            int ly = 4 + q, lx4 = s - q * 10;
            int gy = ty0 + ly - 7;
            int gx = tx0 - 4 + lx4 * 4;
            f32x4 v = {0.f, 0.f, 0.f, 0.f};
            if ((unsigned)gy < (unsigned)H_ && (unsigned)gx < (unsigned)W_)
                v = *(const f32x4*)(sg + (size_t)gy * W_ + gx);
            *(f32x4*)&smlA[ly * SC + 4 + lx4 * 4] = v;
        }
        __syncthreads();
        float* htmp = smlB;
        for (int s = tid; s < 38 * 32; s += 256) {
            int hy = s >> 5, hx = s & 31;
            const float* p = &smlA[(hy + 4)*SC + (hx + 5)];
            htmp[hy*33 + hx] = g7[0]*p[0] + g7[1]*p[1] + g7[2]*p[2] + g7[3]*p[3]
                             + g7[4]*p[4] + g7[5]*p[5] + g7[6]*p[6];
        }
        __syncthreads();
        for (int s = tid; s < TS*TS; s += 256) {
            int oy = s >> 5, ox = s & 31;
            const float* p = &htmp[oy*33 + ox];
            float a = g7[0]*p[0]   + g7[1]*p[33]  + g7[2]*p[66]  + g7[3]*p[99]
                    + g7[4]*p[132] + g7[5]*p[165] + g7[6]*p[198];
            out[(size_t)n*HW_ + (size_t)(ty0 + oy)*W_ + (tx0 + ox)] = a;
        }
        return;
    }

    // ======== COLD PATH ========
    if (bx > 0 && bx < (W_/TS - 1)) {
        for (int s = tid; s < SR * (SC/4); s += 256) {
            int ly = s / (SC/4), j = s - ly * (SC/4);
            int gy = ty0 + ly - 7;
            f32x4 v = {0.f, 0.f, 0.f, 0.f};
            if ((unsigned)gy < (unsigned)H_)
                v = *(const f32x4*)(sg + (size_t)gy * W_ + (tx0 - 8) + j * 4);
            *(f32x4*)&smlA[ly * SC + j * 4] = v;
        }
    } else {
        for (int s = tid; s < SR * SC; s += 256) {
            int ly = s / SC, lx = s - ly * SC;
            int gy = ty0 + ly - 7, gx = tx0 + lx - 8;
            float v = 0.f;
            if ((unsigned)gy < (unsigned)H_ && (unsigned)gx < (unsigned)W_)
                v = sg[(size_t)gy * W_ + gx];
            smlA[ly * SC + lx] = v;
        }
    }
    __syncthreads();

    if (tid < BR) {
        u64 a = M0[tid], u = tid > 0 ? M0[tid-1] : 0, d = tid < BR-1 ? M0[tid+1] : 0;
        E1[tid] = a | (a << 1) | (a >> 1) | u | d;
    }
    __syncthreads();
    if (tid < BR) {
        u64 a = E1[tid], u = tid > 0 ? E1[tid-1] : 0, d = tid < BR-1 ? E1[tid+1] : 0;
        E2[tid] = a | (a << 1) | (a >> 1) | u | d;
    }
    __syncthreads();
    if (tid < BR) {
        u64 a = E2[tid], u = tid > 0 ? E2[tid-1] : 0, d = tid < BR-1 ? E2[tid+1] : 0;
        E3[tid] = a | (a << 1) | (a >> 1) | u | d;
    }
    __syncthreads();
    {
        int r = tid >> 6, i = tid & 63;
        if (i < BR) {
            u64 e = (r == 0) ? M0[i] : (r == 1) ? E1[i] : (r == 2) ? E2[i] : E3[i];
            NBM[r][i] = ~e & VM[i];
        }
    }
    __syncthreads();

    #pragma unroll
    for (int k = 0; k < 4; ++k) {
        const int r = 3 - k;
        const u64 colmask = ((1ULL << (44 - 2*k)) - 1ULL) << (2 + k);
        u64 mwork = 0;
        if (tid >= 1 + k && tid < 45 - k && tid < SR)
            mwork = actRow & colmask;
        u64 mm = mwork;
        while (mm) {
            int lx = __ffsll(mm) - 1; mm &= mm - 1;
            int bi = tid + 3, sh = lx + 1;
            u64 fu = (NBM[r][bi-1] >> sh) & 7ULL;
            u64 fc = (NBM[r][bi  ] >> sh) & 7ULL;
            u64 fd = (NBM[r][bi+1] >> sh) & 7ULL;
            float c = smlA[tid*SC + lx];
            float o;
            if (((fc >> 1) & 1ULL) || !(fu | fc | fd)) {
                o = c;
            } else {
                int cnt = __popcll(fu) + __popcll(fc) + __popcll(fd);
                float sum = 0.f;
                const float* r0 = &smlA[(tid-1)*SC + lx];
                const float* r1 = &smlA[(tid  )*SC + lx];
                const float* r2 = &smlA[(tid+1)*SC + lx];
                if (fu & 1) sum += r0[-1];
                if (fu & 2) sum += r0[0];
                if (fu & 4) sum += r0[1];
                if (fc & 1) sum += r1[-1];
                if (fc & 4) sum += r1[1];
                if (fd & 1) sum += r2[-1];
                if (fd & 2) sum += r2[0];
                if (fd & 4) sum += r2[1];
                o = sum / (float)cnt;
            }
            smlB[tid*SC + lx] = o;
        }
        __syncthreads();
        mm = mwork;
        while (mm) {
            int lx = __ffsll(mm) - 1; mm &= mm - 1;
            smlA[tid*SC + lx] = smlB[tid*SC + lx];
        }
        __syncthreads();
    }

    float* htmp = smlB;
    for (int s = tid; s < 38 * 32; s += 256) {
        int hy = s >> 5, hx = s & 31;
        const float* p = &smlA[(hy + 4)*SC + (hx + 5)];
        htmp[hy*33 + hx] = g7[0]*p[0] + g7[1]*p[1] + g7[2]*p[2] + g7[3]*p[3]
                         + g7[4]*p[4] + g7[5]*p[5] + g7[6]*p[6];
    }
    __syncthreads();
    for (int s = tid; s < TS*TS; s += 256) {
        int oy = s >> 5, ox = s & 31;
        const float* p = &htmp[oy*33 + ox];
        float a = g7[0]*p[0]   + g7[1]*p[33]  + g7[2]*p[66]  + g7[3]*p[99]
                + g7[4]*p[132] + g7[5]*p[165] + g7[6]*p[198];
        out[(size_t)n*HW_ + (size_t)(ty0 + oy)*W_ + (tx0 + ox)] = a;
    }
}

extern "C" void kernel_launch(void* const* d_in, const int* in_sizes, int n_in,
                              void* d_out, int out_size, void* d_ws, size_t ws_size,
                              hipStream_t stream)
{
    const float* x     = (const float*)d_in[0];
    const float* means = (const float*)d_in[1];
    const float* stdv  = (const float*)d_in[2];
    const float* gk    = (const float*)d_in[3];
    float* out_sml  = (float*)d_out;
    float* out_pred = (float*)d_out + NPIX_;

    char* ws = (char*)d_ws;
    float*   sml   = (float*)(ws);                 // 8,388,608 B
    uint8_t* pred8 = (uint8_t*)(ws + 8388608);     // 2,097,152 B
    u64*     bndM  = (u64*)(ws + 10485760);        //   262,144 B

    k_argmax_sml<<<NPIX_/512, 256, 0, stream>>>(x, means, stdv, sml, pred8);
    k_bnd<<<NPIX_/256, 256, 0, stream>>>(pred8, bndM, out_pred);
    dim3 fgrd(W_/TS, H_/TS, N_);
    k_fused<<<fgrd, 256, 0, stream>>>(sml, bndM, gk, out_sml);
}

// Round 15
// 49.455 us; speedup vs baseline: 1.0695x; 1.0253x over previous
//
#include <hip/hip_runtime.h>
#include <cstdint>
#include <cstddef>

#define W_ 512
#define H_ 512
#define N_ 8
#define C_ 19
#define HW_ (W_*H_)      // 262144 = 2^18
#define NPIX_ (N_*HW_)   // 2^21

#define TSX 32           // output tile cols
#define TSY 64           // output tile rows (R15: 32 -> 64 tall)
#define SR  78           // sml region rows (TSY + 14)
#define SC  48           // sml region cols: [tx0-8, tx0+40)
#define BR  84           // bnd-mask rows per tile: [ty0-10, ty0+74)

typedef float   f32x4 __attribute__((ext_vector_type(4)));
typedef float   f32x2 __attribute__((ext_vector_type(2)));
typedef uint8_t u8x2  __attribute__((ext_vector_type(2)));
typedef unsigned long long u64;

// ---------------- K1: channel max/argmax via global_load_lds DMA staging -----
// (unchanged from R14 — at the ~4.9 TB/s multi-stream read ceiling)
__global__ __launch_bounds__(256) void k_argmax_sml(
    const float* __restrict__ x, const float* __restrict__ means,
    const float* __restrict__ stdv, float* __restrict__ sml,
    uint8_t* __restrict__ pred8)
{
    __shared__ float xs[C_ * 512];       // 38,912 B
    __shared__ float ms[C_], rs[C_];
    const int tid = threadIdx.x;
    if (tid < C_) {
        ms[tid] = means[tid];
        rs[tid] = __builtin_amdgcn_rcpf(stdv[tid]);
    }

    const int chunk = blockIdx.x;            // 512 px per block, 4096 blocks
    const int n   = chunk >> 9;
    const int p0  = (chunk & 511) << 9;
    const int wv  = tid >> 6, lane = tid & 63;
    const float* xg = x + (size_t)n * C_ * HW_ + p0;

    int cLo = wv * 5;
    int cHi = cLo + 5 > C_ ? C_ : cLo + 5;   // wave3: 4 channels
    for (int c = cLo; c < cHi; ++c) {
        const float* g = xg + (size_t)c * HW_ + lane * 4;
        #pragma unroll
        for (int t = 0; t < 2; ++t) {
            __builtin_amdgcn_global_load_lds(
                (const __attribute__((address_space(1))) void*)(g + t * 256),
                (__attribute__((address_space(3))) void*)&xs[c * 512 + t * 256],
                16, 0, 0);
        }
    }
    __syncthreads();

    const f32x2* xv = (const f32x2*)xs;
    f32x2 mv = xv[tid];
    int i0 = 0, i1 = 0;
    #pragma unroll
    for (int c = 1; c < C_; ++c) {
        f32x2 v = xv[c * 256 + tid];
        if (v[0] > mv[0]) { mv[0] = v[0]; i0 = c; }
        if (v[1] > mv[1]) { mv[1] = v[1]; i1 = c; }
    }
    const int pix = chunk * 512 + tid * 2;
    f32x2 s; u8x2 pc;
    s[0] = (mv[0] - ms[i0]) * rs[i0];  pc[0] = (uint8_t)i0;
    s[1] = (mv[1] - ms[i1]) * rs[i1];  pc[1] = (uint8_t)i1;
    *(f32x2*)(sml + pix) = s;
    *(u8x2*)(pred8 + pix) = pc;
}

// ---------------- K2: boundary bits -> row masks; also writes predf ----------
__global__ __launch_bounds__(256) void k_bnd(
    const uint8_t* __restrict__ pred8, u64* __restrict__ bndM,
    float* __restrict__ predf)
{
    int gid  = blockIdx.x * 256 + threadIdx.x;
    int lane = gid & 63;
    int wave = gid >> 6;
    int w = wave & 7;
    int y = (wave >> 3) & 511;
    int n = wave >> 12;
    int xx = w * 64 + lane;
    const size_t pix = (size_t)n * HW_ + y * W_ + xx;
    const uint8_t* pc = pred8 + pix;
    int c = pc[0];
    bool u = y > 0, d = y < H_-1, l = xx > 0, r = xx < W_-1;
    int up = u ? pc[-W_] : c;
    int dn = d ? pc[ W_] : c;
    int lf = l ? pc[-1]  : c;
    int rt = r ? pc[ 1]  : c;
    int mx = max(max(c, up), max(dn, max(lf, rt)));       // cross dilate
    int mn = min(min(c, up), min(dn, min(lf, rt)));       // full 3x3 erode
    int c00 = (u && l) ? pc[-W_-1] : c;
    int c01 = (u && r) ? pc[-W_+1] : c;
    int c10 = (d && l) ? pc[ W_-1] : c;
    int c11 = (d && r) ? pc[ W_+1] : c;
    mn = min(mn, min(min(c00, c01), min(c10, c11)));
    __builtin_nontemporal_store((float)c, predf + pix);   // coalesced 256B/wave
    u64 m = __ballot(mx != mn);
    if (lane == 0) bndM[((size_t)n * 512 + y) * 8 + w] = m;
}

// ---------------- K3: fused masks + hot/cold paths + separable conv ----------
// R15: 32x64 tall tiles, 1024 blocks. Column/bit geometry identical to R14;
// row extents scaled (SR 46->78, BR 52->84, 70-row htmp).
__global__ __launch_bounds__(256) void k_fused(
    const float* __restrict__ sml_g, const u64* __restrict__ bndM,
    const float* __restrict__ gk, float* __restrict__ out)
{
    __shared__ float smlA[SR*SC];           // 14,976 B
    __shared__ float smlB[SR*SC];           // staging; aliased as htmp (70*33 fits)
    __shared__ u64 M0[BR], E1[BR], E2[BR], E3[BR], VM[BR];
    __shared__ u64 NBM[4][BR];
    __shared__ float g7[7];
    __shared__ int tACT;

    const int tid = threadIdx.x;
    const int bx = blockIdx.x, by = blockIdx.y, n = blockIdx.z;
    const int tx0 = bx * TSX, ty0 = by * TSY;
    const float* sg = sml_g + (size_t)n * HW_;

    if (tid == 0) tACT = 0;
    if (tid < 7) g7[tid] = gk[21 + tid] / sqrtf(gk[24]);   // kk = outer(g,g)

    // ---- load 84 bnd row-masks (col window [tx0-10, tx0+42)) + validity ----
    if (tid < BR) {
        int gy = ty0 + tid - 10;
        int bx0 = tx0 - 10;
        u64 m = 0, vm = 0;
        if (gy >= 0 && gy < H_) {
            const u64* row = bndM + ((size_t)n * 512 + gy) * 8;
            int sft = bx0 & 63;
            int wi  = bx0 >> 6;                           // arithmetic: -10 -> -1
            u64 w0 = (wi >= 0) ? row[wi] : 0ULL;
            u64 w1 = (wi + 1 <= 7) ? row[wi + 1] : 0ULL;
            m = sft ? ((w0 >> sft) | (w1 << (64 - sft))) : w0;
            int lo = bx0 < 0 ? -bx0 : 0;
            int hi = (512 - bx0) < 52 ? (512 - bx0) : 52; // 52-bit window
            if (hi > lo) vm = ((1ULL << (hi - lo)) - 1ULL) << lo;
        }
        M0[tid] = m;
        VM[tid] = vm;
    }
    __syncthreads();

    // ---- active detection from NB0 = ~M0 & VM ----
    u64 actRow = 0;
    if (tid < SR) {
        int bi = tid + 3;
        u64 nbU = ~M0[bi-1] & VM[bi-1];
        u64 nbC = ~M0[bi  ] & VM[bi  ];
        u64 nbD = ~M0[bi+1] & VM[bi+1];
        u64 U = nbU | nbC | nbD;
        u64 A = (U >> 1) | (U >> 2) | (U >> 3);
        int lo = tx0 == 0 ? 8 : 0;
        int hi = tx0 == (W_-TSX) ? 40 : SC;
        u64 CV = (hi - lo >= 64) ? ~0ULL : (((1ULL << (hi - lo)) - 1ULL) << lo);
        actRow = A & CV;
        int gy = ty0 + tid - 7;
        if ((unsigned)gy >= (unsigned)H_) actRow = 0;
        if (actRow) tACT = 1;                              // benign race
    }
    __syncthreads();

    if (!tACT) {
        // ======== HOT PATH: conv only; load rows [4,74) x cols [4,44) ========
        for (int s = tid; s < 70 * 10; s += 256) {
            int q  = s / 10;
            int ly = 4 + q, lx4 = s - q * 10;
            int gy = ty0 + ly - 7;
            int gx = tx0 - 4 + lx4 * 4;
            f32x4 v = {0.f, 0.f, 0.f, 0.f};
            if ((unsigned)gy < (unsigned)H_ && (unsigned)gx < (unsigned)W_)
                v = *(const f32x4*)(sg + (size_t)gy * W_ + gx);
            *(f32x4*)&smlA[ly * SC + 4 + lx4 * 4] = v;
        }
        __syncthreads();
        float* htmp = smlB;                                // 70 x 32, stride 33
        for (int s = tid; s < 70 * 32; s += 256) {
            int hy = s >> 5, hx = s & 31;
            const float* p = &smlA[(hy + 4)*SC + (hx + 5)];
            htmp[hy*33 + hx] = g7[0]*p[0] + g7[1]*p[1] + g7[2]*p[2] + g7[3]*p[3]
                             + g7[4]*p[4] + g7[5]*p[5] + g7[6]*p[6];
        }
        __syncthreads();
        for (int s = tid; s < TSY*TSX; s += 256) {
            int oy = s >> 5, ox = s & 31;
            const float* p = &htmp[oy*33 + ox];
            float a = g7[0]*p[0]   + g7[1]*p[33]  + g7[2]*p[66]  + g7[3]*p[99]
                    + g7[4]*p[132] + g7[5]*p[165] + g7[6]*p[198];
            __builtin_nontemporal_store(
                a, out + (size_t)n*HW_ + (size_t)(ty0 + oy)*W_ + (tx0 + ox));
        }
        return;
    }

    // ======== COLD PATH ========
    if (bx > 0 && bx < (W_/TSX - 1)) {
        for (int s = tid; s < SR * (SC/4); s += 256) {
            int ly = s / (SC/4), j = s - ly * (SC/4);
            int gy = ty0 + ly - 7;
            f32x4 v = {0.f, 0.f, 0.f, 0.f};
            if ((unsigned)gy < (unsigned)H_)
                v = *(const f32x4*)(sg + (size_t)gy * W_ + (tx0 - 8) + j * 4);
            *(f32x4*)&smlA[ly * SC + j * 4] = v;
        }
    } else {
        for (int s = tid; s < SR * SC; s += 256) {
            int ly = s / SC, lx = s - ly * SC;
            int gy = ty0 + ly - 7, gx = tx0 + lx - 8;
            float v = 0.f;
            if ((unsigned)gy < (unsigned)H_ && (unsigned)gx < (unsigned)W_)
                v = sg[(size_t)gy * W_ + gx];
            smlA[ly * SC + lx] = v;
        }
    }
    __syncthreads();

    if (tid < BR) {
        u64 a = M0[tid], u = tid > 0 ? M0[tid-1] : 0, d = tid < BR-1 ? M0[tid+1] : 0;
        E1[tid] = a | (a << 1) | (a >> 1) | u | d;
    }
    __syncthreads();
    if (tid < BR) {
        u64 a = E1[tid], u = tid > 0 ? E1[tid-1] : 0, d = tid < BR-1 ? E1[tid+1] : 0;
        E2[tid] = a | (a << 1) | (a >> 1) | u | d;
    }
    __syncthreads();
    if (tid < BR) {
        u64 a = E2[tid], u = tid > 0 ? E2[tid-1] : 0, d = tid < BR-1 ? E2[tid+1] : 0;
        E3[tid] = a | (a << 1) | (a >> 1) | u | d;
    }
    __syncthreads();
    // NB_r = ~E_r & valid  (BR=84 > 64, so loop over all 4*84 slots)
    for (int s = tid; s < 4 * BR; s += 256) {
        int r = s / BR, i = s - r * BR;
        u64 e = (r == 0) ? M0[i] : (r == 1) ? E1[i] : (r == 2) ? E2[i] : E3[i];
        NBM[r][i] = ~e & VM[i];
    }
    __syncthreads();

    #pragma unroll
    for (int k = 0; k < 4; ++k) {
        const int r = 3 - k;
        const u64 colmask = ((1ULL << (44 - 2*k)) - 1ULL) << (2 + k);
        u64 mwork = 0;
        if (tid >= 1 + k && tid < SR - 1 - k)
            mwork = actRow & colmask;
        u64 mm = mwork;
        while (mm) {
            int lx = __ffsll(mm) - 1; mm &= mm - 1;
            int bi = tid + 3, sh = lx + 1;
            u64 fu = (NBM[r][bi-1] >> sh) & 7ULL;
            u64 fc = (NBM[r][bi  ] >> sh) & 7ULL;
            u64 fd = (NBM[r][bi+1] >> sh) & 7ULL;
            float c = smlA[tid*SC + lx];
            float o;
            if (((fc >> 1) & 1ULL) || !(fu | fc | fd)) {
                o = c;
            } else {
                int cnt = __popcll(fu) + __popcll(fc) + __popcll(fd);
                float sum = 0.f;
                const float* r0 = &smlA[(tid-1)*SC + lx];
                const float* r1 = &smlA[(tid  )*SC + lx];
                const float* r2 = &smlA[(tid+1)*SC + lx];
                if (fu & 1) sum += r0[-1];
                if (fu & 2) sum += r0[0];
                if (fu & 4) sum += r0[1];
                if (fc & 1) sum += r1[-1];
                if (fc & 4) sum += r1[1];
                if (fd & 1) sum += r2[-1];
                if (fd & 2) sum += r2[0];
                if (fd & 4) sum += r2[1];
                o = sum / (float)cnt;
            }
            smlB[tid*SC + lx] = o;
        }
        __syncthreads();
        mm = mwork;
        while (mm) {
            int lx = __ffsll(mm) - 1; mm &= mm - 1;
            smlA[tid*SC + lx] = smlB[tid*SC + lx];
        }
        __syncthreads();
    }

    float* htmp = smlB;
    for (int s = tid; s < 70 * 32; s += 256) {
        int hy = s >> 5, hx = s & 31;
        const float* p = &smlA[(hy + 4)*SC + (hx + 5)];
        htmp[hy*33 + hx] = g7[0]*p[0] + g7[1]*p[1] + g7[2]*p[2] + g7[3]*p[3]
                         + g7[4]*p[4] + g7[5]*p[5] + g7[6]*p[6];
    }
    __syncthreads();
    for (int s = tid; s < TSY*TSX; s += 256) {
        int oy = s >> 5, ox = s & 31;
        const float* p = &htmp[oy*33 + ox];
        float a = g7[0]*p[0]   + g7[1]*p[33]  + g7[2]*p[66]  + g7[3]*p[99]
                + g7[4]*p[132] + g7[5]*p[165] + g7[6]*p[198];
        __builtin_nontemporal_store(
            a, out + (size_t)n*HW_ + (size_t)(ty0 + oy)*W_ + (tx0 + ox));
    }
}

extern "C" void kernel_launch(void* const* d_in, const int* in_sizes, int n_in,
                              void* d_out, int out_size, void* d_ws, size_t ws_size,
                              hipStream_t stream)
{
    const float* x     = (const float*)d_in[0];
    const float* means = (const float*)d_in[1];
    const float* stdv  = (const float*)d_in[2];
    const float* gk    = (const float*)d_in[3];
    float* out_sml  = (float*)d_out;
    float* out_pred = (float*)d_out + NPIX_;

    char* ws = (char*)d_ws;
    float*   sml   = (float*)(ws);                 // 8,388,608 B
    uint8_t* pred8 = (uint8_t*)(ws + 8388608);     // 2,097,152 B
    u64*     bndM  = (u64*)(ws + 10485760);        //   262,144 B

    k_argmax_sml<<<NPIX_/512, 256, 0, stream>>>(x, means, stdv, sml, pred8);
    k_bnd<<<NPIX_/256, 256, 0, stream>>>(pred8, bndM, out_pred);
    dim3 fgrd(W_/TSX, H_/TSY, N_);
    k_fused<<<fgrd, 256, 0, stream>>>(sml, bndM, gk, out_sml);
}